// Round 15
// baseline (272.317 us; speedup 1.0000x reference)
//
#include <hip/hip_runtime.h>
#include <hip/hip_bf16.h>
#include <math.h>

#define NF    50              // n_frequencies
#define DEMB  10              // embedding dim
#define W1G   (4 * NF * DEMB) // 2000 floats of w1 per gene
#define MAXG  512             // max genes supported by bucket path

#define HTPB   256
#define HCHUNK 4096
#define HFPT   (HCHUNK / HTPB) // 16 fragments per thread in scatter

#define HPAD  11              // fp32 stride of per-wave LDS h tile
#define TKP   208             // transpose tile k-stride (bf16)
#define CSLOT 1024            // bucket capacity per gene (max count ~470)
#define BPG   8               // main blocks per gene (8*4 waves*32 = 1024)

typedef __attribute__((ext_vector_type(8))) short short8v;      // 8 bf16
typedef __attribute__((ext_vector_type(4))) unsigned int uint4v;
typedef __attribute__((ext_vector_type(4))) float f32x4v;

__device__ __forceinline__ short f2bf(float f) {
    union { __hip_bfloat16 b; unsigned short u; } v;
    v.b = __float2bfloat16(f);
    return (short)v.u;
}
__device__ __forceinline__ unsigned pkbf(float lo, float hi) {
    union { __hip_bfloat162 b; unsigned u; } v;
    v.b = __float22bfloat162_rn(make_float2(lo, hi));   // .x -> low half
    return v.u;
}

// ---------------------------------------------------------------------------
// K1: prep — zero gcount, transpose w1 -> bf16 w1T[g][d][k], init out with b2.
// grid = max(n_genes, ceil(total/HTPB)); block bid<n_genes transposes gene bid.
// ---------------------------------------------------------------------------
__global__ __launch_bounds__(HTPB) void prep_k(
    const float* __restrict__ w1, short* __restrict__ w1T,
    int* __restrict__ gcount, float* __restrict__ out,
    const float* __restrict__ b2, const int* __restrict__ genes_oi,
    int n_genes, int gene_n, int total)
{
    __shared__ __align__(16) short tile[DEMB][TKP];
    const int tid = threadIdx.x;
    const int bid = blockIdx.x;

    if (bid == 0) {
        for (int t = tid; t < MAXG; t += HTPB) gcount[t] = 0;
        if (tid < 64) w1T[(size_t)n_genes * 2000 + tid] = 0;  // kk=6 over-read tail
    }

    if (bid < n_genes) {
        const float* wg = w1 + (size_t)bid * W1G;
        for (int e4 = tid; e4 < W1G / 4; e4 += HTPB) {
            float4 v = ((const float4*)wg)[e4];
            int e = e4 * 4;
            int k0 = e / 10, d0 = e - k0 * 10;
#pragma unroll
            for (int c = 0; c < 4; ++c) {
                tile[d0][k0] = f2bf((&v.x)[c]);
                d0++; if (d0 == 10) { d0 = 0; k0++; }
            }
        }
    }

    // init out with broadcast b2 (grid-stride)
    int nthreads = gridDim.x * HTPB;
    for (int i = bid * HTPB + tid; i < total; i += nthreads) {
        int col = (int)((unsigned)i % (unsigned)gene_n);
        out[i] = b2[genes_oi[col]];
    }

    if (bid < n_genes) {
        __syncthreads();
        short* og = w1T + (size_t)bid * 2000;
        for (int o = tid; o < 250; o += HTPB) {
            int dd = o / 25;
            int off = (o - dd * 25) * 8;
            *(short8v*)(og + dd * 200 + off) = *(const short8v*)&tile[dd][off];
        }
    }
}

// ---------------------------------------------------------------------------
// K2: scatter into fixed-capacity per-gene buckets. LDS ranks per block; ONE
// returning global atomic per gene per block reserves [base, base+c) in the
// gene's bucket. Slots [0, count) end up contiguous -> no scan kernel.
// ---------------------------------------------------------------------------
__global__ __launch_bounds__(HTPB) void scatter_k(
    const int* __restrict__ gm, const float* __restrict__ coords,
    const int* __restrict__ lcg, int* __restrict__ gcount,
    float* __restrict__ xs, int* __restrict__ bins,
    int n_frag, int n_genes)
{
    __shared__ int lcnt[MAXG];
    __shared__ int lbase[MAXG];
    for (int t = threadIdx.x; t < MAXG; t += HTPB) lcnt[t] = 0;
    __syncthreads();

    int base = blockIdx.x * HCHUNK;
    int g[HFPT], lr[HFPT];
#pragma unroll
    for (int j = 0; j < HFPT; ++j) {
        int f = base + j * HTPB + (int)threadIdx.x;
        if (f < n_frag) {
            g[j]  = gm[f];
            lr[j] = atomicAdd(&lcnt[g[j]], 1);
        } else {
            g[j] = -1;
        }
    }
    __syncthreads();
    for (int t = threadIdx.x; t < MAXG; t += HTPB) {
        int c = lcnt[t];
        lbase[t] = c ? atomicAdd(&gcount[t], c) : 0;
    }
    __syncthreads();
#pragma unroll
    for (int j = 0; j < HFPT; ++j) {
        if (g[j] >= 0) {
            int f = base + j * HTPB + (int)threadIdx.x;
            int slot = lbase[g[j]] + lr[j];
            if (slot < CSLOT) {                       // never triggers at these sizes
                float2 xy = ((const float2*)coords)[f];
                ((float2*)xs)[(size_t)g[j] * CSLOT + slot] = xy;
                bins[(size_t)g[j] * CSLOT + slot] = lcg[f];
            }
        }
    }
}

// ---------------------------------------------------------------------------
// K3: main (MFMA, r12-proven body) over gene buckets. g = blockIdx / BPG
// (block-uniform, scalar); each of the 4 waves owns one 32-frag group.
// Empty blocks/waves exit on the count check.
// ---------------------------------------------------------------------------
__global__ __launch_bounds__(256, 6) void main_mfma_k(
    const short* __restrict__ w1T, const float* __restrict__ b1,
    const float* __restrict__ w2, const int* __restrict__ genes_oi,
    const float* __restrict__ xs, const int* __restrict__ bins,
    const int* __restrict__ gcount, float* __restrict__ out,
    int gene_n)
{
    __shared__ __align__(16) float fr_ext[116];     // fr[i mod 50]
    __shared__ __align__(16) float hb_all[4][32 * HPAD];

    int g   = blockIdx.x / BPG;
    int sub = blockIdx.x % BPG;
    int count = gcount[g];
    count = (count < CSLOT) ? count : CSLOT;
    if (sub * 128 >= count) return;                 // block-uniform early exit

    if (threadIdx.x < 116) {
        int i = threadIdx.x;
        int im = (i < 50) ? i : ((i < 100) ? i - 50 : i - 100);
        float ex = (-2.0f * (float)(im + 1) / (float)NF) * 9.965784284662087f; // log2(1000)
        fr_ext[i] = exp2f(ex) * 0.15915494309189535f;   // base/(2*pi): revolutions
    }
    __syncthreads();

    int wid  = threadIdx.x >> 6;
    int lane = threadIdx.x & 63;
    int d    = lane & 15;
    int q    = lane >> 4;
    int dc   = (d < 10) ? d : 9;
    int ln32 = lane & 31;

    int base_slot = (sub * 4 + wid) * 32;           // this wave's group
    if (base_slot >= count) return;                 // wave-uniform, after barrier

    int slot = base_slot + ln32;
    bool valid = (lane < 32) && (slot < count);
    float2 xy = valid ? ((const float2*)xs)[(size_t)g * CSLOT + slot]
                      : make_float2(0.0f, 0.0f);
    int bin_own = valid ? bins[(size_t)g * CSLOT + slot] : 0;
    int col_own = (int)((unsigned)bin_own % (unsigned)gene_n);

    // ---- hoisted row-coord broadcasts ----
    float ax[2], ay[2];
#pragma unroll
    for (int m = 0; m < 2; ++m) {
        int srcA = m * 16 + d;
        ax[m] = __shfl(xy.x, srcA);
        ay[m] = __shfl(xy.y, srcA);
    }

    // ---- accumulators init with b1 ----
    float b1v = b1[(size_t)g * DEMB + dc];
    f32x4v acc[2];
#pragma unroll
    for (int m = 0; m < 2; ++m) { acc[m][0] = b1v; acc[m][1] = b1v; acc[m][2] = b1v; acc[m][3] = b1v; }

    // ---- MFMA loop: kk outer (B fragment loaded per-kk), m inner ----
    const short* bp = w1T + (size_t)g * 2000 + dc * 200 + q * 8;
#pragma unroll
    for (int kk = 0; kk < 7; ++kk) {
        short8v bfrag = *(const short8v*)(bp + kk * 32);
        float4 fv4 = *(const float4*)&fr_ext[16 * kk + 4 * q];
#pragma unroll
        for (int m = 0; m < 2; ++m) {
            uint4v au;
#pragma unroll
            for (int jj = 0; jj < 4; ++jj) {
                int idx = 16 * kk + 4 * q + jj;        // k = 2*idx; idx<50 -> coord0
                float fv = (&fv4.x)[jj];
                float xv = (idx < 50) ? ax[m] : ay[m];
                float r = xv * fv; r -= rintf(r);      // revolutions in [-0.5,0.5]
                au[jj] = pkbf(__builtin_amdgcn_sinf(r), __builtin_amdgcn_cosf(r));
            }
            if (kk == 6 && q > 0) {                    // k>=200 pad (lane-uniform)
                au[0] = 0; au[1] = 0; au[2] = 0; au[3] = 0;
            }
            short8v afrag = __builtin_bit_cast(short8v, au);
            acc[m] = __builtin_amdgcn_mfma_f32_16x16x32_bf16(afrag, bfrag, acc[m], 0, 0, 0);
        }
    }

    // ---- epilogue: per-wave LDS h-transpose; lanes 0-31 own fragments ----
    float* hb = hb_all[wid];
    if (d < 10) {                              // junk cols must not write (r9 bug)
#pragma unroll
        for (int m = 0; m < 2; ++m)
#pragma unroll
            for (int r = 0; r < 4; ++r)
                hb[(m * 16 + q * 4 + r) * HPAD + d] = acc[m][r];
    }

    if (lane < 32) {
        int gi = genes_oi[col_own];
        const float* w2r = w2 + (size_t)gi * DEMB;
        float sum = 0.0f;
#pragma unroll
        for (int p2 = 0; p2 < 5; ++p2) {
            float2 wv = *(const float2*)(w2r + 2 * p2);
            float h0 = hb[ln32 * HPAD + 2 * p2];
            float h1 = hb[ln32 * HPAD + 2 * p2 + 1];
            sum += wv.x / (1.0f + __expf(-h0));
            sum += wv.y / (1.0f + __expf(-h1));
        }
        if (valid) atomicAdd(&out[bin_own], sum);
    }
}

// ---------------------------------------------------------------------------
// Tiny-workspace fallback: one thread per fragment, non-uniform gene
// ---------------------------------------------------------------------------
__global__ __launch_bounds__(256) void frag_naive_k(
    const float* __restrict__ coords, const float* __restrict__ w1,
    const float* __restrict__ b1, const float* __restrict__ w2,
    const int* __restrict__ gm, const int* __restrict__ lcg,
    const int* __restrict__ genes_oi, float* __restrict__ out,
    int gene_n, int n_frag)
{
    __shared__ float fr[NF];
    if (threadIdx.x < NF) {
        float ex = (-2.0f * (float)(threadIdx.x + 1) / (float)NF) * 9.965784284662087f;
        fr[threadIdx.x] = exp2f(ex) * 0.15915494309189535f;
    }
    __syncthreads();

    int f = blockIdx.x * blockDim.x + threadIdx.x;
    if (f >= n_frag) return;
    int g = gm[f];
    const float* wrow  = w1 + (size_t)g * W1G;
    const float* b1row = b1 + (size_t)g * DEMB;
    float x0 = coords[2 * f + 0];
    float x1 = coords[2 * f + 1];

    float h[DEMB];
#pragma unroll
    for (int d = 0; d < DEMB; ++d) h[d] = b1row[d];
#pragma unroll 2
    for (int i = 0; i < NF; ++i) {
        float fv = fr[i];
        float r0 = x0 * fv; r0 -= rintf(r0);
        float r1 = x1 * fv; r1 -= rintf(r1);
        float s0 = __builtin_amdgcn_sinf(r0), c0 = __builtin_amdgcn_cosf(r0);
        float s1 = __builtin_amdgcn_sinf(r1), c1 = __builtin_amdgcn_cosf(r1);
        const float* wa = wrow + (2 * i) * DEMB;
        const float* wb = wrow + (2 * NF + 2 * i) * DEMB;
#pragma unroll
        for (int d = 0; d < DEMB; ++d) {
            h[d] += s0 * wa[d] + c0 * wa[DEMB + d] + s1 * wb[d] + c1 * wb[DEMB + d];
        }
    }
    int bin = lcg[f];
    int col = (int)((unsigned)bin % (unsigned)gene_n);
    const float* w2row = w2 + (size_t)genes_oi[col] * DEMB;
    float sum = 0.0f;
#pragma unroll
    for (int d = 0; d < DEMB; ++d) {
        float sg = 1.0f / (1.0f + __expf(-h[d]));
        sum += sg * w2row[d];
    }
    atomicAdd(&out[bin], sum);
}

__global__ void init_out_k(float* __restrict__ out, const float* __restrict__ b2,
                           const int* __restrict__ genes_oi, int gene_n, int total)
{
    int i = blockIdx.x * blockDim.x + threadIdx.x;
    if (i < total) {
        int col = (int)((unsigned)i % (unsigned)gene_n);
        out[i] = b2[genes_oi[col]];
    }
}

// ---------------------------------------------------------------------------
extern "C" void kernel_launch(void* const* d_in, const int* in_sizes, int n_in,
                              void* d_out, int out_size, void* d_ws, size_t ws_size,
                              hipStream_t stream)
{
    const float* coords   = (const float*)d_in[0];
    const float* w1       = (const float*)d_in[1];
    const float* b1       = (const float*)d_in[2];
    const float* w2       = (const float*)d_in[3];
    const float* b2       = (const float*)d_in[4];
    const int*   gm       = (const int*)d_in[5];
    const int*   lcg      = (const int*)d_in[6];
    const int*   genes_oi = (const int*)d_in[7];

    int n_frag  = in_sizes[5];
    int n_genes = in_sizes[4];
    int gene_n  = in_sizes[7];
    int total   = out_size;
    float* out  = (float*)d_out;

    // workspace layout
    short* w1T    = (short*)d_ws;                           // [n_genes*2000 + 64] bf16
    size_t w1T_sh = (size_t)n_genes * 2000 + 64;
    if (w1T_sh & 3) w1T_sh += 4 - (w1T_sh & 3);             // 8B-align next section
    int* gcount   = (int*)(w1T + w1T_sh);                   // [MAXG]
    float* xs     = (float*)(gcount + MAXG);                // [MAXG*CSLOT*2]
    int* bins     = (int*)(xs + (size_t)MAXG * CSLOT * 2);  // [MAXG*CSLOT]
    size_t need = w1T_sh * sizeof(short)
                + (MAXG + (size_t)MAXG * CSLOT * 3) * sizeof(int);

    // expected max per-gene count must fit the bucket (mean + huge slack)
    bool fits = ((size_t)4 * n_frag / (n_genes ? n_genes : 1)) < CSLOT;
    bool use_bucket = (ws_size >= need) && (n_genes <= MAXG) && fits;

    if (use_bucket) {
        int nblk = (n_frag + HCHUNK - 1) / HCHUNK;
        int g1t = (total + HTPB - 1) / HTPB;
        int g1 = (g1t > n_genes) ? g1t : n_genes;
        prep_k<<<g1, HTPB, 0, stream>>>(w1, w1T, gcount, out, b2, genes_oi,
                                        n_genes, gene_n, total);
        scatter_k<<<nblk, HTPB, 0, stream>>>(gm, coords, lcg, gcount,
                                             xs, bins, n_frag, n_genes);
        main_mfma_k<<<n_genes * BPG, 256, 0, stream>>>(w1T, b1, w2, genes_oi,
                                                       xs, bins, gcount, out, gene_n);
    } else {
        init_out_k<<<(total + 255) / 256, 256, 0, stream>>>(out, b2, genes_oi, gene_n, total);
        frag_naive_k<<<(n_frag + 255) / 256, 256, 0, stream>>>(coords, w1, b1, w2, gm, lcg,
                                                               genes_oi, out, gene_n, n_frag);
    }
}

// Round 16
// 73.639 us; speedup vs baseline: 3.6980x; 3.6980x over previous
//
#include <hip/hip_runtime.h>
#include <hip/hip_bf16.h>
#include <math.h>

#define NF    50              // n_frequencies
#define DEMB  10              // embedding dim
#define W1G   (4 * NF * DEMB) // 2000 floats of w1 per gene
#define MAXG  512             // max genes supported by bucket path

#define HTPB   256
#define HCHUNK 4096
#define HFPT   (HCHUNK / HTPB) // 16 fragments per thread in scatter

#define HPAD  11              // fp32 stride of per-wave LDS h tile
#define TKP   208             // transpose tile k-stride (bf16)
#define CSLOT 2048            // bucket capacity per gene (max count ~470; 4x slack)
#define BPG   16              // main blocks per gene (16*4 waves*32 = 2048)

typedef __attribute__((ext_vector_type(8))) short short8v;      // 8 bf16
typedef __attribute__((ext_vector_type(4))) unsigned int uint4v;
typedef __attribute__((ext_vector_type(4))) float f32x4v;

__device__ __forceinline__ short f2bf(float f) {
    union { __hip_bfloat16 b; unsigned short u; } v;
    v.b = __float2bfloat16(f);
    return (short)v.u;
}
__device__ __forceinline__ unsigned pkbf(float lo, float hi) {
    union { __hip_bfloat162 b; unsigned u; } v;
    v.b = __float22bfloat162_rn(make_float2(lo, hi));   // .x -> low half
    return v.u;
}

// ---------------------------------------------------------------------------
// K1: prep — zero gcount, transpose w1 -> bf16 w1T[g][d][k], init out with b2.
// grid = max(n_genes, ceil(total/HTPB)); block bid<n_genes transposes gene bid.
// ---------------------------------------------------------------------------
__global__ __launch_bounds__(HTPB) void prep_k(
    const float* __restrict__ w1, short* __restrict__ w1T,
    int* __restrict__ gcount, float* __restrict__ out,
    const float* __restrict__ b2, const int* __restrict__ genes_oi,
    int n_genes, int gene_n, int total)
{
    __shared__ __align__(16) short tile[DEMB][TKP];
    const int tid = threadIdx.x;
    const int bid = blockIdx.x;

    if (bid == 0) {
        for (int t = tid; t < MAXG; t += HTPB) gcount[t] = 0;
        if (tid < 64) w1T[(size_t)n_genes * 2000 + tid] = 0;  // kk=6 over-read tail
    }

    if (bid < n_genes) {
        const float* wg = w1 + (size_t)bid * W1G;
        for (int e4 = tid; e4 < W1G / 4; e4 += HTPB) {
            float4 v = ((const float4*)wg)[e4];
            int e = e4 * 4;
            int k0 = e / 10, d0 = e - k0 * 10;
#pragma unroll
            for (int c = 0; c < 4; ++c) {
                tile[d0][k0] = f2bf((&v.x)[c]);
                d0++; if (d0 == 10) { d0 = 0; k0++; }
            }
        }
    }

    // init out with broadcast b2 (grid-stride)
    int nthreads = gridDim.x * HTPB;
    for (int i = bid * HTPB + tid; i < total; i += nthreads) {
        int col = (int)((unsigned)i % (unsigned)gene_n);
        out[i] = b2[genes_oi[col]];
    }

    if (bid < n_genes) {
        __syncthreads();
        short* og = w1T + (size_t)bid * 2000;
        for (int o = tid; o < 250; o += HTPB) {
            int dd = o / 25;
            int off = (o - dd * 25) * 8;
            *(short8v*)(og + dd * 200 + off) = *(const short8v*)&tile[dd][off];
        }
    }
}

// ---------------------------------------------------------------------------
// K2: scatter into fixed-capacity per-gene buckets. LDS ranks per block; ONE
// returning global atomic per gene per block reserves [base, base+c) in the
// gene's bucket. Slots [0, count) end up contiguous -> no scan kernel.
// ---------------------------------------------------------------------------
__global__ __launch_bounds__(HTPB) void scatter_k(
    const int* __restrict__ gm, const float* __restrict__ coords,
    const int* __restrict__ lcg, int* __restrict__ gcount,
    float* __restrict__ xs, int* __restrict__ bins,
    int n_frag, int n_genes)
{
    __shared__ int lcnt[MAXG];
    __shared__ int lbase[MAXG];
    for (int t = threadIdx.x; t < MAXG; t += HTPB) lcnt[t] = 0;
    __syncthreads();

    int base = blockIdx.x * HCHUNK;
    int g[HFPT], lr[HFPT];
#pragma unroll
    for (int j = 0; j < HFPT; ++j) {
        int f = base + j * HTPB + (int)threadIdx.x;
        if (f < n_frag) {
            g[j]  = gm[f];
            lr[j] = atomicAdd(&lcnt[g[j]], 1);
        } else {
            g[j] = -1;
        }
    }
    __syncthreads();
    for (int t = threadIdx.x; t < MAXG; t += HTPB) {
        int c = lcnt[t];
        lbase[t] = c ? atomicAdd(&gcount[t], c) : 0;
    }
    __syncthreads();
#pragma unroll
    for (int j = 0; j < HFPT; ++j) {
        if (g[j] >= 0) {
            int f = base + j * HTPB + (int)threadIdx.x;
            int slot = lbase[g[j]] + lr[j];
            if (slot < CSLOT) {                       // never triggers at these sizes
                float2 xy = ((const float2*)coords)[f];
                ((float2*)xs)[(size_t)g[j] * CSLOT + slot] = xy;
                bins[(size_t)g[j] * CSLOT + slot] = lcg[f];
            }
        }
    }
}

// ---------------------------------------------------------------------------
// K3: main (MFMA, r12-proven body) over gene buckets. g = blockIdx / BPG
// (block-uniform, scalar); each of the 4 waves owns one 32-frag group.
// Empty blocks/waves exit on the count check.
// ---------------------------------------------------------------------------
__global__ __launch_bounds__(256, 6) void main_mfma_k(
    const short* __restrict__ w1T, const float* __restrict__ b1,
    const float* __restrict__ w2, const int* __restrict__ genes_oi,
    const float* __restrict__ xs, const int* __restrict__ bins,
    const int* __restrict__ gcount, float* __restrict__ out,
    int gene_n)
{
    __shared__ __align__(16) float fr_ext[116];     // fr[i mod 50]
    __shared__ __align__(16) float hb_all[4][32 * HPAD];

    int g   = blockIdx.x / BPG;
    int sub = blockIdx.x % BPG;
    int count = gcount[g];
    count = (count < CSLOT) ? count : CSLOT;
    if (sub * 128 >= count) return;                 // block-uniform early exit

    if (threadIdx.x < 116) {
        int i = threadIdx.x;
        int im = (i < 50) ? i : ((i < 100) ? i - 50 : i - 100);
        float ex = (-2.0f * (float)(im + 1) / (float)NF) * 9.965784284662087f; // log2(1000)
        fr_ext[i] = exp2f(ex) * 0.15915494309189535f;   // base/(2*pi): revolutions
    }
    __syncthreads();

    int wid  = threadIdx.x >> 6;
    int lane = threadIdx.x & 63;
    int d    = lane & 15;
    int q    = lane >> 4;
    int dc   = (d < 10) ? d : 9;
    int ln32 = lane & 31;

    int base_slot = (sub * 4 + wid) * 32;           // this wave's group
    if (base_slot >= count) return;                 // wave-uniform, after barrier

    int slot = base_slot + ln32;
    bool valid = (lane < 32) && (slot < count);
    float2 xy = valid ? ((const float2*)xs)[(size_t)g * CSLOT + slot]
                      : make_float2(0.0f, 0.0f);
    int bin_own = valid ? bins[(size_t)g * CSLOT + slot] : 0;
    int col_own = (int)((unsigned)bin_own % (unsigned)gene_n);

    // ---- hoisted row-coord broadcasts ----
    float ax[2], ay[2];
#pragma unroll
    for (int m = 0; m < 2; ++m) {
        int srcA = m * 16 + d;
        ax[m] = __shfl(xy.x, srcA);
        ay[m] = __shfl(xy.y, srcA);
    }

    // ---- accumulators init with b1 ----
    float b1v = b1[(size_t)g * DEMB + dc];
    f32x4v acc[2];
#pragma unroll
    for (int m = 0; m < 2; ++m) { acc[m][0] = b1v; acc[m][1] = b1v; acc[m][2] = b1v; acc[m][3] = b1v; }

    // ---- MFMA loop: kk outer (B fragment loaded per-kk), m inner ----
    const short* bp = w1T + (size_t)g * 2000 + dc * 200 + q * 8;
#pragma unroll
    for (int kk = 0; kk < 7; ++kk) {
        short8v bfrag = *(const short8v*)(bp + kk * 32);
        float4 fv4 = *(const float4*)&fr_ext[16 * kk + 4 * q];
#pragma unroll
        for (int m = 0; m < 2; ++m) {
            uint4v au;
#pragma unroll
            for (int jj = 0; jj < 4; ++jj) {
                int idx = 16 * kk + 4 * q + jj;        // k = 2*idx; idx<50 -> coord0
                float fv = (&fv4.x)[jj];
                float xv = (idx < 50) ? ax[m] : ay[m];
                float r = xv * fv; r -= rintf(r);      // revolutions in [-0.5,0.5]
                au[jj] = pkbf(__builtin_amdgcn_sinf(r), __builtin_amdgcn_cosf(r));
            }
            if (kk == 6 && q > 0) {                    // k>=200 pad (lane-uniform)
                au[0] = 0; au[1] = 0; au[2] = 0; au[3] = 0;
            }
            short8v afrag = __builtin_bit_cast(short8v, au);
            acc[m] = __builtin_amdgcn_mfma_f32_16x16x32_bf16(afrag, bfrag, acc[m], 0, 0, 0);
        }
    }

    // ---- epilogue: per-wave LDS h-transpose; lanes 0-31 own fragments ----
    float* hb = hb_all[wid];
    if (d < 10) {                              // junk cols must not write (r9 bug)
#pragma unroll
        for (int m = 0; m < 2; ++m)
#pragma unroll
            for (int r = 0; r < 4; ++r)
                hb[(m * 16 + q * 4 + r) * HPAD + d] = acc[m][r];
    }

    if (lane < 32) {
        int gi = genes_oi[col_own];
        const float* w2r = w2 + (size_t)gi * DEMB;
        float sum = 0.0f;
#pragma unroll
        for (int p2 = 0; p2 < 5; ++p2) {
            float2 wv = *(const float2*)(w2r + 2 * p2);
            float h0 = hb[ln32 * HPAD + 2 * p2];
            float h1 = hb[ln32 * HPAD + 2 * p2 + 1];
            sum += wv.x / (1.0f + __expf(-h0));
            sum += wv.y / (1.0f + __expf(-h1));
        }
        if (valid) atomicAdd(&out[bin_own], sum);
    }
}

// ---------------------------------------------------------------------------
// Tiny-workspace fallback: one thread per fragment, non-uniform gene
// ---------------------------------------------------------------------------
__global__ __launch_bounds__(256) void frag_naive_k(
    const float* __restrict__ coords, const float* __restrict__ w1,
    const float* __restrict__ b1, const float* __restrict__ w2,
    const int* __restrict__ gm, const int* __restrict__ lcg,
    const int* __restrict__ genes_oi, float* __restrict__ out,
    int gene_n, int n_frag)
{
    __shared__ float fr[NF];
    if (threadIdx.x < NF) {
        float ex = (-2.0f * (float)(threadIdx.x + 1) / (float)NF) * 9.965784284662087f;
        fr[threadIdx.x] = exp2f(ex) * 0.15915494309189535f;
    }
    __syncthreads();

    int f = blockIdx.x * blockDim.x + threadIdx.x;
    if (f >= n_frag) return;
    int g = gm[f];
    const float* wrow  = w1 + (size_t)g * W1G;
    const float* b1row = b1 + (size_t)g * DEMB;
    float x0 = coords[2 * f + 0];
    float x1 = coords[2 * f + 1];

    float h[DEMB];
#pragma unroll
    for (int d = 0; d < DEMB; ++d) h[d] = b1row[d];
#pragma unroll 2
    for (int i = 0; i < NF; ++i) {
        float fv = fr[i];
        float r0 = x0 * fv; r0 -= rintf(r0);
        float r1 = x1 * fv; r1 -= rintf(r1);
        float s0 = __builtin_amdgcn_sinf(r0), c0 = __builtin_amdgcn_cosf(r0);
        float s1 = __builtin_amdgcn_sinf(r1), c1 = __builtin_amdgcn_cosf(r1);
        const float* wa = wrow + (2 * i) * DEMB;
        const float* wb = wrow + (2 * NF + 2 * i) * DEMB;
#pragma unroll
        for (int d = 0; d < DEMB; ++d) {
            h[d] += s0 * wa[d] + c0 * wa[DEMB + d] + s1 * wb[d] + c1 * wb[DEMB + d];
        }
    }
    int bin = lcg[f];
    int col = (int)((unsigned)bin % (unsigned)gene_n);
    const float* w2row = w2 + (size_t)genes_oi[col] * DEMB;
    float sum = 0.0f;
#pragma unroll
    for (int d = 0; d < DEMB; ++d) {
        float sg = 1.0f / (1.0f + __expf(-h[d]));
        sum += sg * w2row[d];
    }
    atomicAdd(&out[bin], sum);
}

__global__ void init_out_k(float* __restrict__ out, const float* __restrict__ b2,
                           const int* __restrict__ genes_oi, int gene_n, int total)
{
    int i = blockIdx.x * blockDim.x + threadIdx.x;
    if (i < total) {
        int col = (int)((unsigned)i % (unsigned)gene_n);
        out[i] = b2[genes_oi[col]];
    }
}

// ---------------------------------------------------------------------------
extern "C" void kernel_launch(void* const* d_in, const int* in_sizes, int n_in,
                              void* d_out, int out_size, void* d_ws, size_t ws_size,
                              hipStream_t stream)
{
    const float* coords   = (const float*)d_in[0];
    const float* w1       = (const float*)d_in[1];
    const float* b1       = (const float*)d_in[2];
    const float* w2       = (const float*)d_in[3];
    const float* b2       = (const float*)d_in[4];
    const int*   gm       = (const int*)d_in[5];
    const int*   lcg      = (const int*)d_in[6];
    const int*   genes_oi = (const int*)d_in[7];

    int n_frag  = in_sizes[5];
    int n_genes = in_sizes[4];
    int gene_n  = in_sizes[7];
    int total   = out_size;
    float* out  = (float*)d_out;

    // workspace layout
    short* w1T    = (short*)d_ws;                           // [n_genes*2000 + 64] bf16
    size_t w1T_sh = (size_t)n_genes * 2000 + 64;
    if (w1T_sh & 3) w1T_sh += 4 - (w1T_sh & 3);             // 8B-align next section
    int* gcount   = (int*)(w1T + w1T_sh);                   // [MAXG]
    float* xs     = (float*)(gcount + MAXG);                // [MAXG*CSLOT*2]
    int* bins     = (int*)(xs + (size_t)MAXG * CSLOT * 2);  // [MAXG*CSLOT]
    size_t need = w1T_sh * sizeof(short)
                + (MAXG + (size_t)MAXG * CSLOT * 3) * sizeof(int);

    // expected max per-gene count must fit the bucket (4x mean slack)
    bool fits = ((size_t)4 * n_frag / (size_t)(n_genes ? n_genes : 1)) <= CSLOT;
    bool use_bucket = (ws_size >= need) && (n_genes <= MAXG) && fits;

    if (use_bucket) {
        int nblk = (n_frag + HCHUNK - 1) / HCHUNK;
        int g1t = (total + HTPB - 1) / HTPB;
        int g1 = (g1t > n_genes) ? g1t : n_genes;
        prep_k<<<g1, HTPB, 0, stream>>>(w1, w1T, gcount, out, b2, genes_oi,
                                        n_genes, gene_n, total);
        scatter_k<<<nblk, HTPB, 0, stream>>>(gm, coords, lcg, gcount,
                                             xs, bins, n_frag, n_genes);
        main_mfma_k<<<n_genes * BPG, 256, 0, stream>>>(w1T, b1, w2, genes_oi,
                                                       xs, bins, gcount, out, gene_n);
    } else {
        init_out_k<<<(total + 255) / 256, 256, 0, stream>>>(out, b2, genes_oi, gene_n, total);
        frag_naive_k<<<(n_frag + 255) / 256, 256, 0, stream>>>(coords, w1, b1, w2, gm, lcg,
                                                               genes_oi, out, gene_n, n_frag);
    }
}

// Round 17
// 68.302 us; speedup vs baseline: 3.9869x; 1.0781x over previous
//
#include <hip/hip_runtime.h>
#include <hip/hip_bf16.h>
#include <math.h>

#define NF    50              // n_frequencies
#define DEMB  10              // embedding dim
#define W1G   (4 * NF * DEMB) // 2000 floats of w1 per gene
#define MAXG  512             // max genes supported by bucket path

#define HTPB   256
#define HCHUNK 4096
#define HFPT   (HCHUNK / HTPB) // 16 fragments per thread in scatter

#define HPAD  11              // fp32 stride of per-wave LDS h tile
#define TKP   208             // transpose tile k-stride (bf16)
#define CSLOT 2048            // bucket capacity per gene (max count ~470; 4x slack)
#define BPG   8               // main blocks per gene (8 * 4 waves * 64 = 2048)

typedef __attribute__((ext_vector_type(8))) short short8v;      // 8 bf16
typedef __attribute__((ext_vector_type(4))) unsigned int uint4v;
typedef __attribute__((ext_vector_type(4))) float f32x4v;

__device__ __forceinline__ short f2bf(float f) {
    union { __hip_bfloat16 b; unsigned short u; } v;
    v.b = __float2bfloat16(f);
    return (short)v.u;
}
__device__ __forceinline__ unsigned pkbf(float lo, float hi) {
    union { __hip_bfloat162 b; unsigned u; } v;
    v.b = __float22bfloat162_rn(make_float2(lo, hi));   // .x -> low half
    return v.u;
}

// ---------------------------------------------------------------------------
// K1: prep — zero gcount, transpose w1 -> bf16 w1T[g][d][k], init out with b2.
// ---------------------------------------------------------------------------
__global__ __launch_bounds__(HTPB) void prep_k(
    const float* __restrict__ w1, short* __restrict__ w1T,
    int* __restrict__ gcount, float* __restrict__ out,
    const float* __restrict__ b2, const int* __restrict__ genes_oi,
    int n_genes, int gene_n, int total)
{
    __shared__ __align__(16) short tile[DEMB][TKP];
    const int tid = threadIdx.x;
    const int bid = blockIdx.x;

    if (bid == 0) {
        for (int t = tid; t < MAXG; t += HTPB) gcount[t] = 0;
        if (tid < 64) w1T[(size_t)n_genes * 2000 + tid] = 0;  // kk=6 over-read tail
    }

    if (bid < n_genes) {
        const float* wg = w1 + (size_t)bid * W1G;
        for (int e4 = tid; e4 < W1G / 4; e4 += HTPB) {
            float4 v = ((const float4*)wg)[e4];
            int e = e4 * 4;
            int k0 = e / 10, d0 = e - k0 * 10;
#pragma unroll
            for (int c = 0; c < 4; ++c) {
                tile[d0][k0] = f2bf((&v.x)[c]);
                d0++; if (d0 == 10) { d0 = 0; k0++; }
            }
        }
    }

    // init out with broadcast b2 (grid-stride)
    int nthreads = gridDim.x * HTPB;
    for (int i = bid * HTPB + tid; i < total; i += nthreads) {
        int col = (int)((unsigned)i % (unsigned)gene_n);
        out[i] = b2[genes_oi[col]];
    }

    if (bid < n_genes) {
        __syncthreads();
        short* og = w1T + (size_t)bid * 2000;
        for (int o = tid; o < 250; o += HTPB) {
            int dd = o / 25;
            int off = (o - dd * 25) * 8;
            *(short8v*)(og + dd * 200 + off) = *(const short8v*)&tile[dd][off];
        }
    }
}

// ---------------------------------------------------------------------------
// K2: scatter into fixed-capacity per-gene buckets. LDS ranks per block; ONE
// returning global atomic per gene per block reserves [base, base+c).
// ---------------------------------------------------------------------------
__global__ __launch_bounds__(HTPB) void scatter_k(
    const int* __restrict__ gm, const float* __restrict__ coords,
    const int* __restrict__ lcg, int* __restrict__ gcount,
    float* __restrict__ xs, int* __restrict__ bins,
    int n_frag, int n_genes)
{
    __shared__ int lcnt[MAXG];
    __shared__ int lbase[MAXG];
    for (int t = threadIdx.x; t < MAXG; t += HTPB) lcnt[t] = 0;
    __syncthreads();

    int base = blockIdx.x * HCHUNK;
    int g[HFPT], lr[HFPT];
#pragma unroll
    for (int j = 0; j < HFPT; ++j) {
        int f = base + j * HTPB + (int)threadIdx.x;
        if (f < n_frag) {
            g[j]  = gm[f];
            lr[j] = atomicAdd(&lcnt[g[j]], 1);
        } else {
            g[j] = -1;
        }
    }
    __syncthreads();
    for (int t = threadIdx.x; t < MAXG; t += HTPB) {
        int c = lcnt[t];
        lbase[t] = c ? atomicAdd(&gcount[t], c) : 0;
    }
    __syncthreads();
#pragma unroll
    for (int j = 0; j < HFPT; ++j) {
        if (g[j] >= 0) {
            int f = base + j * HTPB + (int)threadIdx.x;
            int slot = lbase[g[j]] + lr[j];
            if (slot < CSLOT) {                       // never triggers at these sizes
                float2 xy = ((const float2*)coords)[f];
                ((float2*)xs)[(size_t)g[j] * CSLOT + slot] = xy;
                bins[(size_t)g[j] * CSLOT + slot] = lcg[f];
            }
        }
    }
}

// ---------------------------------------------------------------------------
// K3: main (MFMA v6) — 64 frags/wave (4 M-tiles), ALL independent loads
// batched up front (breg[7], xy, bins, b1v; then genes_oi->w2v[5] prefetch),
// launch_bounds(256,4) so the compiler keeps them in flight (~90 VGPR).
// ---------------------------------------------------------------------------
__global__ __launch_bounds__(256, 4) void main_mfma_k(
    const short* __restrict__ w1T, const float* __restrict__ b1,
    const float* __restrict__ w2, const int* __restrict__ genes_oi,
    const float* __restrict__ xs, const int* __restrict__ bins,
    const int* __restrict__ gcount, float* __restrict__ out,
    int gene_n)
{
    __shared__ __align__(16) float fr_ext[116];     // fr[i mod 50]
    __shared__ __align__(16) float hb_all[4][64 * HPAD];

    int g   = blockIdx.x / BPG;
    int sub = blockIdx.x % BPG;
    int count = gcount[g];
    count = (count < CSLOT) ? count : CSLOT;
    if (sub * 256 >= count) return;                 // block-uniform early exit

    if (threadIdx.x < 116) {
        int i = threadIdx.x;
        int im = (i < 50) ? i : ((i < 100) ? i - 50 : i - 100);
        float ex = (-2.0f * (float)(im + 1) / (float)NF) * 9.965784284662087f; // log2(1000)
        fr_ext[i] = exp2f(ex) * 0.15915494309189535f;   // base/(2*pi): revolutions
    }
    __syncthreads();

    int wid  = threadIdx.x >> 6;
    int lane = threadIdx.x & 63;
    int d    = lane & 15;
    int q    = lane >> 4;
    int dc   = (d < 10) ? d : 9;

    int base_slot = (sub * 4 + wid) * 64;           // this wave's 64-frag group
    if (base_slot >= count) return;                 // wave-uniform, after barrier

    int slot = base_slot + lane;
    bool valid = slot < count;

    // ================= batched independent loads (round 1) =================
    float2 xy = valid ? ((const float2*)xs)[(size_t)g * CSLOT + slot]
                      : make_float2(0.0f, 0.0f);
    int bin_own = valid ? bins[(size_t)g * CSLOT + slot] : 0;
    float b1v = b1[(size_t)g * DEMB + dc];
    const short* bp = w1T + (size_t)g * 2000 + dc * 200 + q * 8;
    short8v breg[7];
#pragma unroll
    for (int kk = 0; kk < 7; ++kk)
        breg[kk] = *(const short8v*)(bp + kk * 32);

    // ================= dependent prefetch (round 2) ========================
    int col_own = (int)((unsigned)bin_own % (unsigned)gene_n);
    int gi = genes_oi[col_own];
    float2 w2v[5];
#pragma unroll
    for (int p2 = 0; p2 < 5; ++p2)
        w2v[p2] = *(const float2*)(w2 + (size_t)gi * DEMB + 2 * p2);

    // ---- hoisted row-coord broadcasts (8 bpermutes) ----
    float ax[4], ay[4];
#pragma unroll
    for (int m = 0; m < 4; ++m) {
        int srcA = m * 16 + d;                // fragment whose A-row this lane supplies
        ax[m] = __shfl(xy.x, srcA);
        ay[m] = __shfl(xy.y, srcA);
    }

    // ---- accumulators init with b1 ----
    f32x4v acc[4];
#pragma unroll
    for (int m = 0; m < 4; ++m) { acc[m][0] = b1v; acc[m][1] = b1v; acc[m][2] = b1v; acc[m][3] = b1v; }

    // ---- MFMA loop: kk outer, m inner; freq operands from LDS per kk ----
#pragma unroll
    for (int kk = 0; kk < 7; ++kk) {
        float4 fv4 = *(const float4*)&fr_ext[16 * kk + 4 * q];
#pragma unroll
        for (int m = 0; m < 4; ++m) {
            uint4v au;
#pragma unroll
            for (int jj = 0; jj < 4; ++jj) {
                int idx = 16 * kk + 4 * q + jj;        // k = 2*idx; idx<50 -> coord0
                float fv = (&fv4.x)[jj];
                float xv = (idx < 50) ? ax[m] : ay[m];
                float r = xv * fv; r -= rintf(r);      // revolutions in [-0.5,0.5]
                au[jj] = pkbf(__builtin_amdgcn_sinf(r), __builtin_amdgcn_cosf(r));
            }
            if (kk == 6 && q > 0) {                    // k>=200 pad (lane-uniform)
                au[0] = 0; au[1] = 0; au[2] = 0; au[3] = 0;
            }
            short8v afrag = __builtin_bit_cast(short8v, au);
            acc[m] = __builtin_amdgcn_mfma_f32_16x16x32_bf16(afrag, breg[kk], acc[m], 0, 0, 0);
        }
    }

    // ---- epilogue: per-wave LDS h-transpose; lane owns its fragment ----
    float* hb = hb_all[wid];
    if (d < 10) {                              // junk cols must not write (r9 bug)
#pragma unroll
        for (int m = 0; m < 4; ++m)
#pragma unroll
            for (int r = 0; r < 4; ++r)
                hb[(m * 16 + q * 4 + r) * HPAD + d] = acc[m][r];
    }

    float sum = 0.0f;
#pragma unroll
    for (int p2 = 0; p2 < 5; ++p2) {
        float h0 = hb[lane * HPAD + 2 * p2];
        float h1 = hb[lane * HPAD + 2 * p2 + 1];
        sum += w2v[p2].x / (1.0f + __expf(-h0));
        sum += w2v[p2].y / (1.0f + __expf(-h1));
    }
    if (valid) atomicAdd(&out[bin_own], sum);
}

// ---------------------------------------------------------------------------
// Tiny-workspace fallback: one thread per fragment, non-uniform gene
// ---------------------------------------------------------------------------
__global__ __launch_bounds__(256) void frag_naive_k(
    const float* __restrict__ coords, const float* __restrict__ w1,
    const float* __restrict__ b1, const float* __restrict__ w2,
    const int* __restrict__ gm, const int* __restrict__ lcg,
    const int* __restrict__ genes_oi, float* __restrict__ out,
    int gene_n, int n_frag)
{
    __shared__ float fr[NF];
    if (threadIdx.x < NF) {
        float ex = (-2.0f * (float)(threadIdx.x + 1) / (float)NF) * 9.965784284662087f;
        fr[threadIdx.x] = exp2f(ex) * 0.15915494309189535f;
    }
    __syncthreads();

    int f = blockIdx.x * blockDim.x + threadIdx.x;
    if (f >= n_frag) return;
    int g = gm[f];
    const float* wrow  = w1 + (size_t)g * W1G;
    const float* b1row = b1 + (size_t)g * DEMB;
    float x0 = coords[2 * f + 0];
    float x1 = coords[2 * f + 1];

    float h[DEMB];
#pragma unroll
    for (int d = 0; d < DEMB; ++d) h[d] = b1row[d];
#pragma unroll 2
    for (int i = 0; i < NF; ++i) {
        float fv = fr[i];
        float r0 = x0 * fv; r0 -= rintf(r0);
        float r1 = x1 * fv; r1 -= rintf(r1);
        float s0 = __builtin_amdgcn_sinf(r0), c0 = __builtin_amdgcn_cosf(r0);
        float s1 = __builtin_amdgcn_sinf(r1), c1 = __builtin_amdgcn_cosf(r1);
        const float* wa = wrow + (2 * i) * DEMB;
        const float* wb = wrow + (2 * NF + 2 * i) * DEMB;
#pragma unroll
        for (int d = 0; d < DEMB; ++d) {
            h[d] += s0 * wa[d] + c0 * wa[DEMB + d] + s1 * wb[d] + c1 * wb[DEMB + d];
        }
    }
    int bin = lcg[f];
    int col = (int)((unsigned)bin % (unsigned)gene_n);
    const float* w2row = w2 + (size_t)genes_oi[col] * DEMB;
    float sum = 0.0f;
#pragma unroll
    for (int d = 0; d < DEMB; ++d) {
        float sg = 1.0f / (1.0f + __expf(-h[d]));
        sum += sg * w2row[d];
    }
    atomicAdd(&out[bin], sum);
}

__global__ void init_out_k(float* __restrict__ out, const float* __restrict__ b2,
                           const int* __restrict__ genes_oi, int gene_n, int total)
{
    int i = blockIdx.x * blockDim.x + threadIdx.x;
    if (i < total) {
        int col = (int)((unsigned)i % (unsigned)gene_n);
        out[i] = b2[genes_oi[col]];
    }
}

// ---------------------------------------------------------------------------
extern "C" void kernel_launch(void* const* d_in, const int* in_sizes, int n_in,
                              void* d_out, int out_size, void* d_ws, size_t ws_size,
                              hipStream_t stream)
{
    const float* coords   = (const float*)d_in[0];
    const float* w1       = (const float*)d_in[1];
    const float* b1       = (const float*)d_in[2];
    const float* w2       = (const float*)d_in[3];
    const float* b2       = (const float*)d_in[4];
    const int*   gm       = (const int*)d_in[5];
    const int*   lcg      = (const int*)d_in[6];
    const int*   genes_oi = (const int*)d_in[7];

    int n_frag  = in_sizes[5];
    int n_genes = in_sizes[4];
    int gene_n  = in_sizes[7];
    int total   = out_size;
    float* out  = (float*)d_out;

    // workspace layout
    short* w1T    = (short*)d_ws;                           // [n_genes*2000 + 64] bf16
    size_t w1T_sh = (size_t)n_genes * 2000 + 64;
    if (w1T_sh & 3) w1T_sh += 4 - (w1T_sh & 3);             // 8B-align next section
    int* gcount   = (int*)(w1T + w1T_sh);                   // [MAXG]
    float* xs     = (float*)(gcount + MAXG);                // [MAXG*CSLOT*2]
    int* bins     = (int*)(xs + (size_t)MAXG * CSLOT * 2);  // [MAXG*CSLOT]
    size_t need = w1T_sh * sizeof(short)
                + (MAXG + (size_t)MAXG * CSLOT * 3) * sizeof(int);

    // expected max per-gene count must fit the bucket (4x mean slack)
    bool fits = ((size_t)4 * n_frag / (size_t)(n_genes ? n_genes : 1)) <= CSLOT;
    bool use_bucket = (ws_size >= need) && (n_genes <= MAXG) && fits;

    if (use_bucket) {
        int nblk = (n_frag + HCHUNK - 1) / HCHUNK;
        int g1t = (total + HTPB - 1) / HTPB;
        int g1 = (g1t > n_genes) ? g1t : n_genes;
        prep_k<<<g1, HTPB, 0, stream>>>(w1, w1T, gcount, out, b2, genes_oi,
                                        n_genes, gene_n, total);
        scatter_k<<<nblk, HTPB, 0, stream>>>(gm, coords, lcg, gcount,
                                             xs, bins, n_frag, n_genes);
        main_mfma_k<<<n_genes * BPG, 256, 0, stream>>>(w1T, b1, w2, genes_oi,
                                                       xs, bins, gcount, out, gene_n);
    } else {
        init_out_k<<<(total + 255) / 256, 256, 0, stream>>>(out, b2, genes_oi, gene_n, total);
        frag_naive_k<<<(n_frag + 255) / 256, 256, 0, stream>>>(coords, w1, b1, w2, gm, lcg,
                                                               genes_oi, out, gene_n, n_frag);
    }
}

// Round 18
// 45.339 us; speedup vs baseline: 6.0063x; 1.5065x over previous
//
#include <hip/hip_runtime.h>
#include <hip/hip_bf16.h>
#include <math.h>

#define NF    50              // n_frequencies
#define DEMB  10              // embedding dim
#define W1G   (4 * NF * DEMB) // 2000 floats of w1 per gene
#define MAXG  512             // max genes supported by sort path

#define HTPB   256
#define HCHUNK 4096
#define HFPT   (HCHUNK / HTPB) // 16 fragments per thread in hist/scatter

#define HPAD  11              // fp32 stride of per-wave LDS h tile
#define TKP   208             // transpose tile k-stride (bf16)

typedef __attribute__((ext_vector_type(8))) short short8v;      // 8 bf16
typedef __attribute__((ext_vector_type(4))) unsigned int uint4v;
typedef __attribute__((ext_vector_type(4))) float f32x4v;

__device__ __forceinline__ short f2bf(float f) {
    union { __hip_bfloat16 b; unsigned short u; } v;
    v.b = __float2bfloat16(f);
    return (short)v.u;
}
__device__ __forceinline__ unsigned pkbf(float lo, float hi) {
    union { __hip_bfloat162 b; unsigned u; } v;
    v.b = __float22bfloat162_rn(make_float2(lo, hi));   // .x -> low half
    return v.u;
}

// ---------------------------------------------------------------------------
// K1: per-block private histogram rows + out init with b2 + w1 transpose.
// ---------------------------------------------------------------------------
__global__ __launch_bounds__(HTPB) void hist_init_k(
    const int* __restrict__ gm, const float* __restrict__ w1,
    short* __restrict__ w1T, int n_frag, int n_genes, int nblk,
    int* __restrict__ counts_mat,                 // [nblk][MAXG]
    float* __restrict__ out, const float* __restrict__ b2,
    const int* __restrict__ genes_oi, int gene_n, int total)
{
    __shared__ int lcnt[MAXG];
    __shared__ __align__(16) short tile[DEMB][TKP];

    bool do_hist = (int)blockIdx.x < nblk;
    bool do_tr   = (int)blockIdx.x < n_genes;

    for (int t = threadIdx.x; t < MAXG; t += HTPB) lcnt[t] = 0;
    __syncthreads();

    if (do_hist) {
        int base = blockIdx.x * HCHUNK;
#pragma unroll
        for (int j = 0; j < HFPT; ++j) {
            int f = base + j * HTPB + (int)threadIdx.x;
            if (f < n_frag) atomicAdd(&lcnt[gm[f]], 1);
        }
    }

    if (do_tr) {
        const float* wg = w1 + (size_t)blockIdx.x * W1G;
        for (int e4 = threadIdx.x; e4 < W1G / 4; e4 += HTPB) {
            float4 v = ((const float4*)wg)[e4];
            int e = e4 * 4;
            int k0 = e / 10, d0 = e - k0 * 10;
#pragma unroll
            for (int c = 0; c < 4; ++c) {
                tile[d0][k0] = f2bf((&v.x)[c]);
                d0++; if (d0 == 10) { d0 = 0; k0++; }
            }
        }
    }

    // init out with broadcast b2 (grid-stride)
    int nthreads = gridDim.x * HTPB;
    for (int i = blockIdx.x * HTPB + (int)threadIdx.x; i < total; i += nthreads) {
        int col = (int)((unsigned)i % (unsigned)gene_n);
        out[i] = b2[genes_oi[col]];
    }
    // zero the small tail after w1T (over-read by kk=6 B loads)
    if (blockIdx.x == 0 && threadIdx.x < 64)
        w1T[(size_t)n_genes * 2000 + threadIdx.x] = 0;

    __syncthreads();

    if (do_hist) {
        int* row = counts_mat + (size_t)blockIdx.x * MAXG;
        for (int t = threadIdx.x; t < MAXG; t += HTPB) row[t] = lcnt[t];
    }
    if (do_tr) {
        short* og = w1T + (size_t)blockIdx.x * 2000;
        for (int o = threadIdx.x; o < 250; o += HTPB) {
            int dd = o / 25;
            int off = (o - dd * 25) * 8;
            *(short8v*)(og + dd * 200 + off) = *(const short8v*)&tile[dd][off];
        }
    }
}

// ---------------------------------------------------------------------------
// K2: reduce count matrix; scan of 64-PADDED counts; build per-wave tables:
// w2g[w] = gene of wave w, wlim[w] = number of VALID lanes in wave w.
// ---------------------------------------------------------------------------
__global__ void scan_k(const int* __restrict__ counts_mat, int nblk,
                       int* __restrict__ po, int* __restrict__ cursor,
                       int* __restrict__ cnt, int* __restrict__ w2g,
                       int* __restrict__ wlim, int n_genes, int wmax)
{
    __shared__ int buf[MAXG];
    int tid = threadIdx.x;
    int s = 0;
#pragma unroll 8
    for (int b = 0; b < nblk; ++b) s += counts_mat[(size_t)b * MAXG + tid];
    int pc = ((s + 63) >> 6) << 6;       // padded count (64)
    buf[tid] = pc;
    __syncthreads();
    for (int d = 1; d < MAXG; d <<= 1) {
        int t = (tid >= d) ? buf[tid - d] : 0;
        __syncthreads();
        buf[tid] += t;
        __syncthreads();
    }
    int incl = buf[tid];
    if (tid < n_genes) {
        po[tid + 1] = incl;
        cursor[tid] = incl - pc;
        cnt[tid]    = s;
        int wbeg = (incl - pc) >> 6;
        int wend = incl >> 6;
        for (int w = wbeg; w < wend; ++w) {
            w2g[w]  = tid;
            wlim[w] = s - (w - wbeg) * 64;   // >=64 means all lanes valid
        }
    }
    if (tid == 0) po[0] = 0;
    __syncthreads();
    int W = buf[n_genes - 1] >> 6;
    for (int w = W + tid; w < wmax; w += MAXG) w2g[w] = -1;
}

// ---------------------------------------------------------------------------
// K3: scatter packed records (coords, bin) into padded gene-sorted order.
// ---------------------------------------------------------------------------
__global__ __launch_bounds__(HTPB) void scatter_k(
    const int* __restrict__ gm, const float* __restrict__ coords,
    const int* __restrict__ lcg, int* __restrict__ cursor,
    float* __restrict__ xs, int* __restrict__ bins,
    int n_frag, int n_genes)
{
    __shared__ int lcnt[MAXG];
    __shared__ int lbase[MAXG];
    for (int t = threadIdx.x; t < MAXG; t += HTPB) lcnt[t] = 0;
    __syncthreads();

    int base = blockIdx.x * HCHUNK;
    int g[HFPT], lr[HFPT];
#pragma unroll
    for (int j = 0; j < HFPT; ++j) {
        int f = base + j * HTPB + (int)threadIdx.x;
        if (f < n_frag) {
            g[j]  = gm[f];
            lr[j] = atomicAdd(&lcnt[g[j]], 1);
        } else {
            g[j] = -1;
        }
    }
    __syncthreads();
    for (int t = threadIdx.x; t < MAXG; t += HTPB) {
        int c = lcnt[t];
        lbase[t] = c ? atomicAdd(&cursor[t], c) : 0;
    }
    __syncthreads();
#pragma unroll
    for (int j = 0; j < HFPT; ++j) {
        if (g[j] >= 0) {
            int f = base + j * HTPB + (int)threadIdx.x;
            int pos = lbase[g[j]] + lr[j];
            float2 xy = ((const float2*)coords)[f];
            xs[2 * pos + 0] = xy.x;
            xs[2 * pos + 1] = xy.y;
            bins[pos] = lcg[f];
        }
    }
}

// ---------------------------------------------------------------------------
// K4: main (MFMA v7) — 64 frags/wave, 4 M-tiles, SCHEDULER-ENFORCED batching:
// all 13 independent loads issued up front, then sched_barrier(0) prevents
// the compiler from sinking them into the MFMA loop (r16/r17: VGPR=32 showed
// it serialized them). A-row coords loaded DIRECTLY from xs (no bpermutes).
// ---------------------------------------------------------------------------
__global__ __launch_bounds__(256, 4) void main_mfma_k(
    const short* __restrict__ w1T, const float* __restrict__ b1,
    const float* __restrict__ w2, const int* __restrict__ genes_oi,
    const float* __restrict__ xs, const int* __restrict__ bins,
    const int* __restrict__ w2g, const int* __restrict__ wlim,
    float* __restrict__ out, int gene_n, int wmax)
{
    __shared__ __align__(16) float fr_ext[116];     // fr[i mod 50]
    __shared__ __align__(16) float hb_all[4][64 * HPAD];

    if (threadIdx.x < 116) {
        int i = threadIdx.x;
        int im = (i < 50) ? i : ((i < 100) ? i - 50 : i - 100);
        float ex = (-2.0f * (float)(im + 1) / (float)NF) * 9.965784284662087f; // log2(1000)
        fr_ext[i] = exp2f(ex) * 0.15915494309189535f;   // base/(2*pi): revolutions
    }
    __syncthreads();

    int wid  = threadIdx.x >> 6;
    int lane = threadIdx.x & 63;
    int fw   = blockIdx.x * 4 + wid;          // frag-wave index

    int g   = (fw < wmax) ? w2g[fw]  : -1;
    int lim = (fw < wmax) ? wlim[fw] : 0;     // independent of g chain
    g = __builtin_amdgcn_readfirstlane(g);
    if (g < 0) return;                        // after the only barrier

    int d  = lane & 15;                       // output dim / B col
    int q  = lane >> 4;                       // k-group
    int dc = (d < 10) ? d : 9;                // clamped dim (cols 10-15 junk)

    bool valid = lane < lim;
    int pos = fw * 64 + lane;

    // ================= round-1: 13 independent loads, then pin =============
    int bin_own = bins[pos];                              // pad slots: garbage, masked later
    float2 xy_m[4];
#pragma unroll
    for (int m = 0; m < 4; ++m)
        xy_m[m] = ((const float2*)xs)[fw * 64 + m * 16 + d];   // A-row coords, direct
    float b1v = b1[(size_t)g * DEMB + dc];
    const short* bp = w1T + (size_t)g * 2000 + dc * 200 + q * 8;
    short8v breg[7];
#pragma unroll
    for (int kk = 0; kk < 7; ++kk)
        breg[kk] = *(const short8v*)(bp + kk * 32);
    __builtin_amdgcn_sched_barrier(0);        // do NOT sink these loads

    // ================= round-2: dependent w2 prefetch ======================
    int col_own = (int)((unsigned)bin_own % (unsigned)gene_n);
    int gi = genes_oi[col_own];
    float2 w2v[5];
#pragma unroll
    for (int p2 = 0; p2 < 5; ++p2)
        w2v[p2] = *(const float2*)(w2 + (size_t)gi * DEMB + 2 * p2);
    __builtin_amdgcn_sched_barrier(0);        // keep prefetch ahead of A-gen

    // ---- accumulators init with b1 ----
    f32x4v acc[4];
#pragma unroll
    for (int m = 0; m < 4; ++m) { acc[m][0] = b1v; acc[m][1] = b1v; acc[m][2] = b1v; acc[m][3] = b1v; }

    // ---- MFMA loop: kk outer, m inner; freq operands from LDS per kk ----
#pragma unroll
    for (int kk = 0; kk < 7; ++kk) {
        float4 fv4 = *(const float4*)&fr_ext[16 * kk + 4 * q];
#pragma unroll
        for (int m = 0; m < 4; ++m) {
            uint4v au;
#pragma unroll
            for (int jj = 0; jj < 4; ++jj) {
                int idx = 16 * kk + 4 * q + jj;        // k = 2*idx; idx<50 -> coord0
                float fv = (&fv4.x)[jj];
                float xv = (idx < 50) ? xy_m[m].x : xy_m[m].y;
                float r = xv * fv; r -= rintf(r);      // revolutions in [-0.5,0.5]
                au[jj] = pkbf(__builtin_amdgcn_sinf(r), __builtin_amdgcn_cosf(r));
            }
            if (kk == 6 && q > 0) {                    // k>=200 pad (lane-uniform)
                au[0] = 0; au[1] = 0; au[2] = 0; au[3] = 0;
            }
            short8v afrag = __builtin_bit_cast(short8v, au);
            acc[m] = __builtin_amdgcn_mfma_f32_16x16x32_bf16(afrag, breg[kk], acc[m], 0, 0, 0);
        }
    }

    // ---- epilogue: per-wave LDS h-transpose; lane owns its fragment ----
    float* hb = hb_all[wid];
    if (d < 10) {                              // junk cols must not write (r9 bug)
#pragma unroll
        for (int m = 0; m < 4; ++m)
#pragma unroll
            for (int r = 0; r < 4; ++r)
                hb[(m * 16 + q * 4 + r) * HPAD + d] = acc[m][r];
    }

    float sum = 0.0f;
#pragma unroll
    for (int p2 = 0; p2 < 5; ++p2) {
        float h0 = hb[lane * HPAD + 2 * p2];
        float h1 = hb[lane * HPAD + 2 * p2 + 1];
        sum += w2v[p2].x / (1.0f + __expf(-h0));
        sum += w2v[p2].y / (1.0f + __expf(-h1));
    }
    if (valid) atomicAdd(&out[bin_own], sum);
}

// ---------------------------------------------------------------------------
// Tiny-workspace fallback: one thread per fragment, non-uniform gene
// ---------------------------------------------------------------------------
__global__ __launch_bounds__(256) void frag_naive_k(
    const float* __restrict__ coords, const float* __restrict__ w1,
    const float* __restrict__ b1, const float* __restrict__ w2,
    const int* __restrict__ gm, const int* __restrict__ lcg,
    const int* __restrict__ genes_oi, float* __restrict__ out,
    int gene_n, int n_frag)
{
    __shared__ float fr[NF];
    if (threadIdx.x < NF) {
        float ex = (-2.0f * (float)(threadIdx.x + 1) / (float)NF) * 9.965784284662087f;
        fr[threadIdx.x] = exp2f(ex) * 0.15915494309189535f;
    }
    __syncthreads();

    int f = blockIdx.x * blockDim.x + threadIdx.x;
    if (f >= n_frag) return;
    int g = gm[f];
    const float* wrow  = w1 + (size_t)g * W1G;
    const float* b1row = b1 + (size_t)g * DEMB;
    float x0 = coords[2 * f + 0];
    float x1 = coords[2 * f + 1];

    float h[DEMB];
#pragma unroll
    for (int d = 0; d < DEMB; ++d) h[d] = b1row[d];
#pragma unroll 2
    for (int i = 0; i < NF; ++i) {
        float fv = fr[i];
        float r0 = x0 * fv; r0 -= rintf(r0);
        float r1 = x1 * fv; r1 -= rintf(r1);
        float s0 = __builtin_amdgcn_sinf(r0), c0 = __builtin_amdgcn_cosf(r0);
        float s1 = __builtin_amdgcn_sinf(r1), c1 = __builtin_amdgcn_cosf(r1);
        const float* wa = wrow + (2 * i) * DEMB;
        const float* wb = wrow + (2 * NF + 2 * i) * DEMB;
#pragma unroll
        for (int d = 0; d < DEMB; ++d) {
            h[d] += s0 * wa[d] + c0 * wa[DEMB + d] + s1 * wb[d] + c1 * wb[DEMB + d];
        }
    }
    int bin = lcg[f];
    int col = (int)((unsigned)bin % (unsigned)gene_n);
    const float* w2row = w2 + (size_t)genes_oi[col] * DEMB;
    float sum = 0.0f;
#pragma unroll
    for (int d = 0; d < DEMB; ++d) {
        float sg = 1.0f / (1.0f + __expf(-h[d]));
        sum += sg * w2row[d];
    }
    atomicAdd(&out[bin], sum);
}

__global__ void init_out_k(float* __restrict__ out, const float* __restrict__ b2,
                           const int* __restrict__ genes_oi, int gene_n, int total)
{
    int i = blockIdx.x * blockDim.x + threadIdx.x;
    if (i < total) {
        int col = (int)((unsigned)i % (unsigned)gene_n);
        out[i] = b2[genes_oi[col]];
    }
}

// ---------------------------------------------------------------------------
extern "C" void kernel_launch(void* const* d_in, const int* in_sizes, int n_in,
                              void* d_out, int out_size, void* d_ws, size_t ws_size,
                              hipStream_t stream)
{
    const float* coords   = (const float*)d_in[0];
    const float* w1       = (const float*)d_in[1];
    const float* b1       = (const float*)d_in[2];
    const float* w2       = (const float*)d_in[3];
    const float* b2       = (const float*)d_in[4];
    const int*   gm       = (const int*)d_in[5];
    const int*   lcg      = (const int*)d_in[6];
    const int*   genes_oi = (const int*)d_in[7];

    int n_frag  = in_sizes[5];
    int n_genes = in_sizes[4];
    int gene_n  = in_sizes[7];
    int total   = out_size;
    float* out  = (float*)d_out;

    int nblk = (n_frag + HCHUNK - 1) / HCHUNK;
    int wmax = (n_frag >> 6) + n_genes + 1;            // upper bound on frag-waves
    size_t padcap = (size_t)n_frag + 64 * (size_t)n_genes + 64;

    // workspace layout
    short* w1T      = (short*)d_ws;                        // [n_genes*2000 + 64] bf16
    size_t w1T_sh   = (size_t)n_genes * 2000 + 64;
    if (w1T_sh & 1) ++w1T_sh;
    int* counts_mat = (int*)(w1T + w1T_sh);                // [nblk][MAXG]
    int* po         = counts_mat + (size_t)nblk * MAXG;    // [MAXG+1]
    int* cursor     = po + (MAXG + 1);                     // [MAXG]
    int* cnt        = cursor + MAXG;                       // [MAXG]
    int* w2g        = cnt + MAXG;                          // [wmax]
    int* wlim       = w2g + wmax;                          // [wmax]
    float* xs       = (float*)(wlim + wmax);               // [2*padcap]
    int* bins       = (int*)(xs + 2 * padcap);             // [padcap]
    size_t need = w1T_sh * sizeof(short)
                + ((size_t)nblk * MAXG + (MAXG + 1) + 2 * MAXG + 2 * (size_t)wmax
                   + 3 * padcap) * sizeof(int);

    bool use_sorted = (ws_size >= need) && (n_genes <= MAXG);
    if (use_sorted) {
        int g1 = (nblk > n_genes) ? nblk : n_genes;
        hist_init_k<<<g1, HTPB, 0, stream>>>(gm, w1, w1T, n_frag, n_genes, nblk,
                                             counts_mat, out, b2, genes_oi, gene_n, total);
        scan_k<<<1, MAXG, 0, stream>>>(counts_mat, nblk, po, cursor, cnt, w2g,
                                       wlim, n_genes, wmax);
        scatter_k<<<nblk, HTPB, 0, stream>>>(gm, coords, lcg, cursor,
                                             xs, bins, n_frag, n_genes);
        int mblk = (wmax + 3) / 4;
        main_mfma_k<<<mblk, 256, 0, stream>>>(w1T, b1, w2, genes_oi, xs, bins,
                                              w2g, wlim, out, gene_n, wmax);
    } else {
        init_out_k<<<(total + 255) / 256, 256, 0, stream>>>(out, b2, genes_oi, gene_n, total);
        frag_naive_k<<<(n_frag + 255) / 256, 256, 0, stream>>>(coords, w1, b1, w2, gm, lcg,
                                                               genes_oi, out, gene_n, n_frag);
    }
}